// Round 1
// baseline (79.775 us; speedup 1.0000x reference)
//
#include <hip/hip_runtime.h>

// Problem constants (from reference)
constexpr int HEAD_DIM      = 128;
constexpr int NUM_HEADS     = 32;
constexpr int NUM_KV_HEADS  = 8;
constexpr int SEQ_LEN       = 8192;
constexpr int ROW_IN        = NUM_HEADS * HEAD_DIM + 2 * NUM_KV_HEADS * HEAD_DIM; // 6144
constexpr int HEADS_PER_ROW = NUM_HEADS + 2 * NUM_KV_HEADS;                        // 48
constexpr float EPS         = 1e-6f;

// Output layout (flat concat of the reference tuple):
//   q_rope: SEQ_LEN*NUM_HEADS*HEAD_DIM     = 33554432 floats at offset 0
//   k_rope: SEQ_LEN*NUM_KV_HEADS*HEAD_DIM  =  8388608 floats at offset 33554432
//   v     : SEQ_LEN*NUM_KV_HEADS*HEAD_DIM  =  8388608 floats at offset 41943040
constexpr size_t Q_OUT_OFF = 0;
constexpr size_t K_OUT_OFF = (size_t)SEQ_LEN * NUM_HEADS * HEAD_DIM;
constexpr size_t V_OUT_OFF = K_OUT_OFF + (size_t)SEQ_LEN * NUM_KV_HEADS * HEAD_DIM;

// One 32-lane half-wave per head (128 floats = 32 lanes x float4).
// Heads per row: [0,32) = Q (norm+rope), [32,40) = K (norm+rope), [40,48) = V (copy).
// Input offset for head h of row r is uniformly r*6144 + h*128.
__global__ __launch_bounds__(256) void qknorm_rope_v_kernel(
    const float* __restrict__ qkv,
    const float* __restrict__ q_w, const float* __restrict__ k_w,
    const float* __restrict__ q_b, const float* __restrict__ k_b,
    const float* __restrict__ cos_w, const float* __restrict__ sin_w,
    float* __restrict__ out)
{
    const int tid  = blockIdx.x * blockDim.x + threadIdx.x;
    const int gh   = tid >> 5;        // global head index (32 lanes per head)
    const int lane = tid & 31;        // lane within head-group

    const int row = gh / HEADS_PER_ROW;
    const int h   = gh - row * HEADS_PER_ROW;
    if (row >= SEQ_LEN) return;

    // Coalesced float4 load: half-wave covers one contiguous 512B head.
    const float4 x = *reinterpret_cast<const float4*>(
        qkv + (size_t)row * ROW_IN + (size_t)h * HEAD_DIM + lane * 4);

    if (h >= NUM_HEADS + NUM_KV_HEADS) {
        // V head: pure copy
        float* vp = out + V_OUT_OFF + (size_t)row * (NUM_KV_HEADS * HEAD_DIM)
                  + (size_t)(h - 40) * HEAD_DIM + lane * 4;
        *reinterpret_cast<float4*>(vp) = x;
        return;
    }

    // ---- RMSNorm: mean of x^2 over the 128-elem head ----
    float sq = x.x * x.x + x.y * x.y + x.z * x.z + x.w * x.w;
    #pragma unroll
    for (int o = 16; o >= 1; o >>= 1)
        sq += __shfl_xor(sq, o, 64);   // masks <=16 stay within the 32-lane half
    const float rnorm = rsqrtf(sq * (1.0f / 128.0f) + EPS);

    const bool isQ = (h < NUM_HEADS);
    const float4 w = reinterpret_cast<const float4*>(isQ ? q_w : k_w)[lane];
    const float4 b = reinterpret_cast<const float4*>(isQ ? q_b : k_b)[lane];

    float4 xn;
    xn.x = x.x * rnorm * w.x + b.x;
    xn.y = x.y * rnorm * w.y + b.y;
    xn.z = x.z * rnorm * w.z + b.z;
    xn.w = x.w * rnorm * w.w + b.w;

    // ---- RoPE: element d pairs with d^64 -> lane j^16 ----
    float4 p;
    p.x = __shfl_xor(xn.x, 16, 64);
    p.y = __shfl_xor(xn.y, 16, 64);
    p.z = __shfl_xor(xn.z, 16, 64);
    p.w = __shfl_xor(xn.w, 16, 64);

    const float4 c = reinterpret_cast<const float4*>(cos_w)[lane];
    const float4 s = reinterpret_cast<const float4*>(sin_w)[lane];
    const float sgn = (lane < 16) ? -1.0f : 1.0f; // first half: -x2*sin; second: +x1*sin

    float4 o;
    o.x = xn.x * c.x + sgn * p.x * s.x;
    o.y = xn.y * c.y + sgn * p.y * s.y;
    o.z = xn.z * c.z + sgn * p.z * s.z;
    o.w = xn.w * c.w + sgn * p.w * s.w;

    float* op;
    if (isQ) {
        op = out + Q_OUT_OFF + (size_t)row * (NUM_HEADS * HEAD_DIM)
           + (size_t)h * HEAD_DIM + lane * 4;
    } else {
        op = out + K_OUT_OFF + (size_t)row * (NUM_KV_HEADS * HEAD_DIM)
           + (size_t)(h - NUM_HEADS) * HEAD_DIM + lane * 4;
    }
    *reinterpret_cast<float4*>(op) = o;
}

extern "C" void kernel_launch(void* const* d_in, const int* in_sizes, int n_in,
                              void* d_out, int out_size, void* d_ws, size_t ws_size,
                              hipStream_t stream) {
    const float* qkv   = (const float*)d_in[0];
    const float* q_w   = (const float*)d_in[1];
    const float* k_w   = (const float*)d_in[2];
    const float* q_b   = (const float*)d_in[3];
    const float* k_b   = (const float*)d_in[4];
    const float* cos_w = (const float*)d_in[5];
    const float* sin_w = (const float*)d_in[6];
    float* out = (float*)d_out;

    const int total_heads   = SEQ_LEN * HEADS_PER_ROW;       // 393216
    const int total_threads = total_heads * 32;               // 12582912
    const int block = 256;
    const int grid  = (total_threads + block - 1) / block;    // 49152

    qknorm_rope_v_kernel<<<grid, block, 0, stream>>>(
        qkv, q_w, k_w, q_b, k_b, cos_w, sin_w, out);
}